// Round 3
// baseline (355.268 us; speedup 1.0000x reference)
//
#include <hip/hip_runtime.h>

// B=4,S=2048,H=16,D=64. scores/8, mask->1e-20(~0), softmax, PV.
// Round 3: qt=2 per wave (4096 waves) + full-step register double-buffer of the
// mask stream (8KB/wave in flight -> mask HBM latency fully hidden). Issue order:
// kf/vf (L2) loads first, then NT mask prefetch, so vmcnt waits for K/V leave the
// mask loads outstanding across the step's compute. Prepack K/V->bf16 frags fused
// into one kernel. No-max softmax (masked = exp2(0) = 1, matches ref 1e-20).

typedef __attribute__((ext_vector_type(8))) short short8;
typedef __attribute__((ext_vector_type(4))) float f32x4;
typedef __attribute__((ext_vector_type(4))) int   i32x4;

#define MFMA(a, b, c) __builtin_amdgcn_mfma_f32_16x16x32_bf16((a), (b), (c), 0, 0, 0)

static __device__ __forceinline__ short f2bf(float f) {
    __bf16 h = (__bf16)f;
    return __builtin_bit_cast(short, h);
}

constexpr int S_ = 2048, HD_ = 1024, STEPS_ = 32;
constexpr long KP_ELEMS = 64L * 32 * 4 * 2 * 64 * 8;   // 8,388,608 bf16 per tensor

// ---- fused prepack: thread t packs K-fragment t and V-fragment t.
// K layout: t = bh*16384 + step*512 + kt*128 + hf*64 + lane; lane=(g,c)
//   holds K[b, step*64+kt*16+c, h, hf*32+g*8 .. +7]
// V layout: t = bh*16384 + step*512 + dt*128 + hf*64 + lane; element i:
//   row = step*64 + hf*32 + (i<4 ? g*4+i : 16+g*4+(i-4)), col = dt*16+c  (kappa order)
__global__ __launch_bounds__(256) void prepack_kv(const float* __restrict__ K,
                                                  const float* __restrict__ V,
                                                  short* __restrict__ Kp,
                                                  short* __restrict__ Vp) {
    int t = blockIdx.x * 256 + threadIdx.x;
    int lane = t & 63, hf = (t >> 6) & 1, kt = (t >> 7) & 3, step = (t >> 9) & 31, bh = t >> 14;
    int g = lane >> 4, c = lane & 15, b = bh >> 4, h = bh & 15;

    {   // K
        int row = step * 64 + kt * 16 + c;
        const float* src = K + (long)(b * S_ + row) * HD_ + h * 64 + hf * 32 + g * 8;
        f32x4 x0 = *(const f32x4*)src, x1 = *(const f32x4*)(src + 4);
        short8 o;
        o[0] = f2bf(x0[0]); o[1] = f2bf(x0[1]); o[2] = f2bf(x0[2]); o[3] = f2bf(x0[3]);
        o[4] = f2bf(x1[0]); o[5] = f2bf(x1[1]); o[6] = f2bf(x1[2]); o[7] = f2bf(x1[3]);
        *(short8*)(Kp + (long)t * 8) = o;
    }
    {   // V (kt plays the role of dt)
        int col = kt * 16 + c, row0 = step * 64 + hf * 32;
        const float* vb = V + (long)(b * S_) * HD_ + h * 64 + col;
        short8 o;
#pragma unroll
        for (int i = 0; i < 8; ++i) {
            int row = row0 + ((i < 4) ? g * 4 + i : 16 + g * 4 + (i - 4));
            o[i] = f2bf(vb[(long)row * HD_]);
        }
        *(short8*)(Vp + (long)t * 8) = o;
    }
}

// ---- hot kernel: 1024 blocks, 4 waves, 32 q-rows per wave
__global__ __launch_bounds__(256, 2)
void attn_fwd3(const float* __restrict__ Q, const short* __restrict__ Kp,
               const short* __restrict__ Vp, const int* __restrict__ M,
               float* __restrict__ O)
{
    const float QSCALE = 0.125f * 1.44269504088896340736f;  // 1/sqrt(64) * log2(e)

    // XCD-bijective swizzle (1024 % 8 == 0): each XCD owns 8 heads -> Kp/Vp L2-resident
    int orig = blockIdx.x;
    int wg   = (orig & 7) * 128 + (orig >> 3);
    int bh   = wg >> 4;          // 0..63
    int qb   = wg & 15;          // 0..15
    int b    = bh >> 4, h = bh & 15;

    int lane = threadIdx.x & 63, wave = threadIdx.x >> 6;
    int g = lane >> 4, c = lane & 15;
    int q0 = qb * 128 + wave * 32;

    const float* qbase = Q + (long)(b * S_) * HD_ + h * 64;
    const int*   mbase = M + ((long)bh << 22);
    float*       obase = O + (long)(b * S_) * HD_ + h * 64;
    const short* kpb   = Kp + (long)bh * STEPS_ * 4096;
    const short* vpb   = Vp + (long)bh * STEPS_ * 4096;

    // Q fragments (B-operand): lane holds Q[q0+qt*16+c][hf*32+g*8 ..+7] * QSCALE
    short8 qf[2][2];
#pragma unroll
    for (int qt = 0; qt < 2; ++qt) {
        const float* qr = qbase + (long)(q0 + qt * 16 + c) * HD_;
#pragma unroll
        for (int hf = 0; hf < 2; ++hf) {
            f32x4 x0 = *(const f32x4*)(qr + hf * 32 + g * 8);
            f32x4 x1 = *(const f32x4*)(qr + hf * 32 + g * 8 + 4);
            short8 t;
            t[0] = f2bf(x0[0] * QSCALE); t[1] = f2bf(x0[1] * QSCALE);
            t[2] = f2bf(x0[2] * QSCALE); t[3] = f2bf(x0[3] * QSCALE);
            t[4] = f2bf(x1[0] * QSCALE); t[5] = f2bf(x1[1] * QSCALE);
            t[6] = f2bf(x1[2] * QSCALE); t[7] = f2bf(x1[3] * QSCALE);
            qf[qt][hf] = t;
        }
    }

    f32x4 acc[2][4];
#pragma unroll
    for (int qt = 0; qt < 2; ++qt)
#pragma unroll
        for (int dt = 0; dt < 4; ++dt) acc[qt][dt] = (f32x4){0.f, 0.f, 0.f, 0.f};
    float lsum[2] = {0.f, 0.f};

    // current-step mask registers: mk[qt][kt], lane holds M[q0+qt*16+c][kv0+kt*16+g*4 ..+3]
    i32x4 mk[2][4];
#pragma unroll
    for (int qt = 0; qt < 2; ++qt) {
        const int* mp = mbase + ((long)(q0 + qt * 16 + c) << 11) + g * 4;
#pragma unroll
        for (int kt = 0; kt < 4; ++kt)
            mk[qt][kt] = __builtin_nontemporal_load((const i32x4*)(mp + kt * 16));
    }

#pragma unroll 1
    for (int step = 0; step < STEPS_; ++step) {
        // 1) K/V fragment loads for this step (L2-resident) — issued FIRST so the
        //    vmcnt wait for them leaves the mask prefetch outstanding.
        const short* kp = kpb + (long)step * 4096;
        const short* vp = vpb + (long)step * 4096;
        short8 kf[4][2], vf[4][2];
#pragma unroll
        for (int kt = 0; kt < 4; ++kt)
#pragma unroll
            for (int hf = 0; hf < 2; ++hf) {
                kf[kt][hf] = *(const short8*)(kp + ((kt * 2 + hf) * 64 + lane) * 8);
                vf[kt][hf] = *(const short8*)(vp + ((kt * 2 + hf) * 64 + lane) * 8);
            }

        // 2) next-step mask prefetch (NT, stays in flight across this step's compute)
        int nstep = (step < STEPS_ - 1) ? step + 1 : step;
        i32x4 mnext[2][4];
#pragma unroll
        for (int qt = 0; qt < 2; ++qt) {
            const int* mpn = mbase + ((long)(q0 + qt * 16 + c) << 11) + nstep * 64 + g * 4;
#pragma unroll
            for (int kt = 0; kt < 4; ++kt)
                mnext[qt][kt] = __builtin_nontemporal_load((const i32x4*)(mpn + kt * 16));
        }

        // 3) compute on current step
#pragma unroll
        for (int qt = 0; qt < 2; ++qt) {
            f32x4 st[4];
#pragma unroll
            for (int kt = 0; kt < 4; ++kt) {
                f32x4 z = (f32x4){0.f, 0.f, 0.f, 0.f};
                z = MFMA(kf[kt][0], qf[qt][0], z);
                z = MFMA(kf[kt][1], qf[qt][1], z);
                st[kt] = z;   // kv = step*64+kt*16+g*4+r, q = q0+qt*16+c (log2e-scaled)
            }

            float p[4][4];
            float s = 0.f;
#pragma unroll
            for (int kt = 0; kt < 4; ++kt)
#pragma unroll
                for (int r = 0; r < 4; ++r) {
                    float val = (mk[qt][kt][r] != 0) ? st[kt][r] : 0.0f;  // masked -> exp2(0)=1
                    float e = exp2f(val);
                    p[kt][r] = e;
                    s += e;
                }
            lsum[qt] += s;

            short8 pb0, pb1;
            pb0[0] = f2bf(p[0][0]); pb0[1] = f2bf(p[0][1]); pb0[2] = f2bf(p[0][2]); pb0[3] = f2bf(p[0][3]);
            pb0[4] = f2bf(p[1][0]); pb0[5] = f2bf(p[1][1]); pb0[6] = f2bf(p[1][2]); pb0[7] = f2bf(p[1][3]);
            pb1[0] = f2bf(p[2][0]); pb1[1] = f2bf(p[2][1]); pb1[2] = f2bf(p[2][2]); pb1[3] = f2bf(p[2][3]);
            pb1[4] = f2bf(p[3][0]); pb1[5] = f2bf(p[3][1]); pb1[6] = f2bf(p[3][2]); pb1[7] = f2bf(p[3][3]);

#pragma unroll
            for (int dt = 0; dt < 4; ++dt) {
                acc[qt][dt] = MFMA(vf[dt][0], pb0, acc[qt][dt]);
                acc[qt][dt] = MFMA(vf[dt][1], pb1, acc[qt][dt]);
            }
        }

        // 4) rotate mask double-buffer
#pragma unroll
        for (int qt = 0; qt < 2; ++qt)
#pragma unroll
            for (int kt = 0; kt < 4; ++kt) mk[qt][kt] = mnext[qt][kt];
    }

    // epilogue: reduce row sums across g-groups, normalize, store
#pragma unroll
    for (int qt = 0; qt < 2; ++qt) {
        float t0 = lsum[qt];
        t0 += __shfl_xor(t0, 16);
        t0 += __shfl_xor(t0, 32);
        float inv = 1.0f / t0;
        float* orow = obase + (long)(q0 + qt * 16 + c) * HD_;
#pragma unroll
        for (int dt = 0; dt < 4; ++dt) {
            f32x4 o = acc[qt][dt] * inv;
            __builtin_nontemporal_store(o, (f32x4*)(orow + dt * 16 + g * 4));
        }
    }
}

// ---- round-1 style fallback (only if ws too small; unchanged math) ----
__global__ __launch_bounds__(256, 2)
void attn_fwd(const float* __restrict__ Q, const float* __restrict__ K,
              const float* __restrict__ V, const int* __restrict__ M,
              float* __restrict__ O)
{
    const float QSCALE = 0.125f * 1.44269504088896340736f;
    int orig = blockIdx.x;
    int wg   = (orig & 7) * 64 + (orig >> 3);
    int bh   = wg >> 3, qb = wg & 7;
    int b    = bh >> 4, h = bh & 15;
    int lane = threadIdx.x & 63, wave = threadIdx.x >> 6;
    int g = lane >> 4, c = lane & 15;
    int q0 = qb * 256 + wave * 64;

    const float* qbase = Q + (long)(b * S_) * HD_ + h * 64;
    const float* kbase = K + (long)(b * S_) * HD_ + h * 64;
    const float* vbase = V + (long)(b * S_) * HD_ + h * 64;
    const int*   mbase = M + ((long)bh << 22);
    float*       obase = O + (long)(b * S_) * HD_ + h * 64;

    short8 qf[4][2];
#pragma unroll
    for (int qt = 0; qt < 4; ++qt) {
        const float* qr = qbase + (long)(q0 + qt * 16 + c) * HD_;
#pragma unroll
        for (int hf = 0; hf < 2; ++hf) {
            f32x4 x0 = *(const f32x4*)(qr + hf * 32 + g * 8);
            f32x4 x1 = *(const f32x4*)(qr + hf * 32 + g * 8 + 4);
            short8 t;
            t[0] = f2bf(x0[0] * QSCALE); t[1] = f2bf(x0[1] * QSCALE);
            t[2] = f2bf(x0[2] * QSCALE); t[3] = f2bf(x0[3] * QSCALE);
            t[4] = f2bf(x1[0] * QSCALE); t[5] = f2bf(x1[1] * QSCALE);
            t[6] = f2bf(x1[2] * QSCALE); t[7] = f2bf(x1[3] * QSCALE);
            qf[qt][hf] = t;
        }
    }

    f32x4 acc[4][4];
#pragma unroll
    for (int qt = 0; qt < 4; ++qt)
#pragma unroll
        for (int dt = 0; dt < 4; ++dt) acc[qt][dt] = (f32x4){0.f, 0.f, 0.f, 0.f};
    float lsum[4] = {0.f, 0.f, 0.f, 0.f};

#pragma unroll 1
    for (int step = 0; step < STEPS_; ++step) {
        int kv0 = step * 64;
        short8 kf[4][2];
#pragma unroll
        for (int kt = 0; kt < 4; ++kt) {
            const float* kr = kbase + (long)(kv0 + kt * 16 + c) * HD_;
#pragma unroll
            for (int hf = 0; hf < 2; ++hf) {
                f32x4 x0 = *(const f32x4*)(kr + hf * 32 + g * 8);
                f32x4 x1 = *(const f32x4*)(kr + hf * 32 + g * 8 + 4);
                short8 t;
                t[0] = f2bf(x0[0]); t[1] = f2bf(x0[1]); t[2] = f2bf(x0[2]); t[3] = f2bf(x0[3]);
                t[4] = f2bf(x1[0]); t[5] = f2bf(x1[1]); t[6] = f2bf(x1[2]); t[7] = f2bf(x1[3]);
                kf[kt][hf] = t;
            }
        }
        short8 vf[4][2];
#pragma unroll
        for (int hf = 0; hf < 2; ++hf) {
            const float* vr[8];
#pragma unroll
            for (int i = 0; i < 4; ++i) {
                vr[i]     = vbase + (long)(kv0 + hf * 32 + g * 4 + i) * HD_ + c;
                vr[4 + i] = vbase + (long)(kv0 + hf * 32 + 16 + g * 4 + i) * HD_ + c;
            }
#pragma unroll
            for (int dt = 0; dt < 4; ++dt) {
                short8 t;
#pragma unroll
                for (int i = 0; i < 8; ++i) t[i] = f2bf(vr[i][dt * 16]);
                vf[dt][hf] = t;
            }
        }
#pragma unroll
        for (int qt = 0; qt < 4; ++qt) {
            f32x4 st[4];
#pragma unroll
            for (int kt = 0; kt < 4; ++kt) {
                f32x4 z = (f32x4){0.f, 0.f, 0.f, 0.f};
                z = MFMA(kf[kt][0], qf[qt][0], z);
                z = MFMA(kf[kt][1], qf[qt][1], z);
                st[kt] = z;
            }
            const int* mrp = mbase + ((long)(q0 + qt * 16 + c) << 11) + kv0 + g * 4;
            float p[4][4];
            float s = 0.f;
#pragma unroll
            for (int kt = 0; kt < 4; ++kt) {
                i32x4 mkv = *(const i32x4*)(mrp + kt * 16);
#pragma unroll
                for (int r = 0; r < 4; ++r) {
                    float val = (mkv[r] != 0) ? st[kt][r] : 0.0f;
                    float e = exp2f(val);
                    p[kt][r] = e;
                    s += e;
                }
            }
            lsum[qt] += s;
            short8 pb0, pb1;
            pb0[0] = f2bf(p[0][0]); pb0[1] = f2bf(p[0][1]); pb0[2] = f2bf(p[0][2]); pb0[3] = f2bf(p[0][3]);
            pb0[4] = f2bf(p[1][0]); pb0[5] = f2bf(p[1][1]); pb0[6] = f2bf(p[1][2]); pb0[7] = f2bf(p[1][3]);
            pb1[0] = f2bf(p[2][0]); pb1[1] = f2bf(p[2][1]); pb1[2] = f2bf(p[2][2]); pb1[3] = f2bf(p[2][3]);
            pb1[4] = f2bf(p[3][0]); pb1[5] = f2bf(p[3][1]); pb1[6] = f2bf(p[3][2]); pb1[7] = f2bf(p[3][3]);
#pragma unroll
            for (int dt = 0; dt < 4; ++dt) {
                acc[qt][dt] = MFMA(vf[dt][0], pb0, acc[qt][dt]);
                acc[qt][dt] = MFMA(vf[dt][1], pb1, acc[qt][dt]);
            }
        }
    }
#pragma unroll
    for (int qt = 0; qt < 4; ++qt) {
        float t0 = lsum[qt];
        t0 += __shfl_xor(t0, 16);
        t0 += __shfl_xor(t0, 32);
        float inv = 1.0f / t0;
        float* orow = obase + (long)(q0 + qt * 16 + c) * HD_;
#pragma unroll
        for (int dt = 0; dt < 4; ++dt) {
            f32x4 o = acc[qt][dt] * inv;
            *(f32x4*)(orow + dt * 16 + g * 4) = o;
        }
    }
}

extern "C" void kernel_launch(void* const* d_in, const int* in_sizes, int n_in,
                              void* d_out, int out_size, void* d_ws, size_t ws_size,
                              hipStream_t stream) {
    const float* q = (const float*)d_in[0];
    const float* k = (const float*)d_in[1];
    const float* v = (const float*)d_in[2];
    const int*   m = (const int*)d_in[3];
    float* out = (float*)d_out;

    size_t need = (size_t)2 * KP_ELEMS * sizeof(short);   // 32 MiB
    if (ws_size >= need) {
        short* Kp = (short*)d_ws;
        short* Vp = Kp + KP_ELEMS;
        prepack_kv<<<dim3(4096), dim3(256), 0, stream>>>(k, v, Kp, Vp);
        attn_fwd3<<<dim3(1024), dim3(256), 0, stream>>>(q, Kp, Vp, m, out);
    } else {
        attn_fwd<<<dim3(512), dim3(256), 0, stream>>>(q, k, v, m, out);
    }
}

// Round 4
// 351.670 us; speedup vs baseline: 1.0102x; 1.0102x over previous
//
#include <hip/hip_runtime.h>

// B=4,S=2048,H=16,D=64. scores/8, mask->1e-20(~0), softmax, PV.
// Round 4 (two-phase): (1) compress 1GB int32 mask -> 33.5MB bitmask with a
// trivially BW-saturating stream kernel (fill-kernel shape, ~6.4 TB/s);
// (2) attention kernel (round-2 qt=4 geometry) reads 8B of mask bits per
// lane per 64-kv step -> mask MLP problem eliminated, K/V L2-resident.
// Masked positions -> exp2(0)=1, matching ref's 1e-20 pre-softmax semantics.

typedef __attribute__((ext_vector_type(8))) short short8;
typedef __attribute__((ext_vector_type(4))) float f32x4;
typedef __attribute__((ext_vector_type(4))) int   i32x4;
typedef unsigned int       u32;
typedef unsigned long long u64;

#define MFMA(a, b, c) __builtin_amdgcn_mfma_f32_16x16x32_bf16((a), (b), (c), 0, 0, 0)

static __device__ __forceinline__ short f2bf(float f) {
    __bf16 h = (__bf16)f;
    return __builtin_bit_cast(short, h);
}

constexpr int S_ = 2048, HD_ = 1024, STEPS_ = 32;
constexpr long KP_ELEMS = 64L * 32 * 4 * 2 * 64 * 8;   // 8,388,608 bf16 per tensor
constexpr long BM_WORDS = 64L * 2048 * 64;             // 8,388,608 u32 (33.5 MB)

// ---- fused prepack: thread t packs K-fragment t and V-fragment t (as rounds 2/3).
__global__ __launch_bounds__(256) void prepack_kv(const float* __restrict__ K,
                                                  const float* __restrict__ V,
                                                  short* __restrict__ Kp,
                                                  short* __restrict__ Vp) {
    int t = blockIdx.x * 256 + threadIdx.x;
    int lane = t & 63, hf = (t >> 6) & 1, kt = (t >> 7) & 3, step = (t >> 9) & 31, bh = t >> 14;
    int g = lane >> 4, c = lane & 15, b = bh >> 4, h = bh & 15;

    {   // K: lane holds K[b, step*64+kt*16+c, h, hf*32+g*8 .. +7]
        int row = step * 64 + kt * 16 + c;
        const float* src = K + (long)(b * S_ + row) * HD_ + h * 64 + hf * 32 + g * 8;
        f32x4 x0 = *(const f32x4*)src, x1 = *(const f32x4*)(src + 4);
        short8 o;
        o[0] = f2bf(x0[0]); o[1] = f2bf(x0[1]); o[2] = f2bf(x0[2]); o[3] = f2bf(x0[3]);
        o[4] = f2bf(x1[0]); o[5] = f2bf(x1[1]); o[6] = f2bf(x1[2]); o[7] = f2bf(x1[3]);
        *(short8*)(Kp + (long)t * 8) = o;
    }
    {   // V (kt plays dt): kappa-ordered V^T fragment
        int col = kt * 16 + c, row0 = step * 64 + hf * 32;
        const float* vb = V + (long)(b * S_) * HD_ + h * 64 + col;
        short8 o;
#pragma unroll
        for (int i = 0; i < 8; ++i) {
            int row = row0 + ((i < 4) ? g * 4 + i : 16 + g * 4 + (i - 4));
            o[i] = f2bf(vb[(long)row * HD_]);
        }
        *(short8*)(Vp + (long)t * 8) = o;
    }
}

// ---- phase 1: mask -> bitmask. Flat mapping: BM[t] bit j = (M[t*32+j] != 0).
// Each thread: 128 B contiguous read (8x i32x4), 4 B write. Pure HBM stream.
__global__ __launch_bounds__(256) void compress_mask(const int* __restrict__ M,
                                                     u32* __restrict__ BM) {
    long t = (long)blockIdx.x * 256 + threadIdx.x;   // 8,388,608 threads
    const i32x4* src = (const i32x4*)(M + (t << 5));
    u32 wd = 0;
#pragma unroll
    for (int j = 0; j < 8; ++j) {
        i32x4 m = src[j];
#pragma unroll
        for (int r = 0; r < 4; ++r)
            wd |= (m[r] != 0 ? 1u : 0u) << (j * 4 + r);
    }
    BM[t] = wd;
}

// ---- phase 2: attention. 512 blocks x 256 thr; wave owns 64 q-rows.
__global__ __launch_bounds__(256, 2)
void attn_fwd4(const float* __restrict__ Q, const short* __restrict__ Kp,
               const short* __restrict__ Vp, const u32* __restrict__ BM,
               float* __restrict__ O)
{
    const float QSCALE = 0.125f * 1.44269504088896340736f;  // 1/sqrt(64) * log2(e)

    // XCD swizzle: XCD i gets bh 8i..8i+7; all 8 q-blocks of a head co-resident
    int orig = blockIdx.x;
    int wg   = (orig & 7) * 64 + (orig >> 3);
    int bh   = wg >> 3, qb = wg & 7;
    int b    = bh >> 4, h = bh & 15;

    int lane = threadIdx.x & 63, wave = threadIdx.x >> 6;
    int g = lane >> 4, c = lane & 15;
    int q0 = qb * 256 + wave * 64;

    const float* qbase = Q + (long)(b * S_) * HD_ + h * 64;
    float*       obase = O + (long)(b * S_) * HD_ + h * 64;
    const short* kpb   = Kp + (long)bh * STEPS_ * 4096;
    const short* vpb   = Vp + (long)bh * STEPS_ * 4096;

    // per-qt bitmask row pointers: u64 per step = bits for 64 kv positions
    const u64* bmp[4];
#pragma unroll
    for (int qt = 0; qt < 4; ++qt)
        bmp[qt] = (const u64*)(BM + ((long)bh * 2048 + q0 + qt * 16 + c) * 64);

    // Q fragments (B-operand): lane holds Q[q0+qt*16+c][hf*32+g*8 ..+7] * QSCALE
    short8 qf[4][2];
#pragma unroll
    for (int qt = 0; qt < 4; ++qt) {
        const float* qr = qbase + (long)(q0 + qt * 16 + c) * HD_;
#pragma unroll
        for (int hf = 0; hf < 2; ++hf) {
            f32x4 x0 = *(const f32x4*)(qr + hf * 32 + g * 8);
            f32x4 x1 = *(const f32x4*)(qr + hf * 32 + g * 8 + 4);
            short8 t;
            t[0] = f2bf(x0[0] * QSCALE); t[1] = f2bf(x0[1] * QSCALE);
            t[2] = f2bf(x0[2] * QSCALE); t[3] = f2bf(x0[3] * QSCALE);
            t[4] = f2bf(x1[0] * QSCALE); t[5] = f2bf(x1[1] * QSCALE);
            t[6] = f2bf(x1[2] * QSCALE); t[7] = f2bf(x1[3] * QSCALE);
            qf[qt][hf] = t;
        }
    }

    f32x4 acc[4][4];
#pragma unroll
    for (int qt = 0; qt < 4; ++qt)
#pragma unroll
        for (int dt = 0; dt < 4; ++dt) acc[qt][dt] = (f32x4){0.f, 0.f, 0.f, 0.f};
    float lsum[4] = {0.f, 0.f, 0.f, 0.f};

    // current-step mask bits (1 u64 per qt)
    u64 bmc[4];
#pragma unroll
    for (int qt = 0; qt < 4; ++qt) bmc[qt] = bmp[qt][0];

#pragma unroll 1
    for (int step = 0; step < STEPS_; ++step) {
        // 1) K/V fragment loads (L2-resident), issued first
        const short* kp = kpb + (long)step * 4096;
        const short* vp = vpb + (long)step * 4096;
        short8 kf[4][2], vf[4][2];
#pragma unroll
        for (int kt = 0; kt < 4; ++kt)
#pragma unroll
            for (int hf = 0; hf < 2; ++hf) {
                kf[kt][hf] = *(const short8*)(kp + ((kt * 2 + hf) * 64 + lane) * 8);
                vf[kt][hf] = *(const short8*)(vp + ((kt * 2 + hf) * 64 + lane) * 8);
            }
        __builtin_amdgcn_sched_barrier(0);

        // 2) next-step bitmask prefetch (stays in flight across this step's compute)
        int nstep = (step < STEPS_ - 1) ? step + 1 : step;
        u64 bmn[4];
#pragma unroll
        for (int qt = 0; qt < 4; ++qt) bmn[qt] = bmp[qt][nstep];
        __builtin_amdgcn_sched_barrier(0);

        // 3) compute
#pragma unroll
        for (int qt = 0; qt < 4; ++qt) {
            f32x4 st[4];
#pragma unroll
            for (int kt = 0; kt < 4; ++kt) {
                f32x4 z = (f32x4){0.f, 0.f, 0.f, 0.f};
                z = MFMA(kf[kt][0], qf[qt][0], z);
                z = MFMA(kf[kt][1], qf[qt][1], z);
                st[kt] = z;   // kv = step*64+kt*16+g*4+r, q = q0+qt*16+c (log2e-scaled)
            }

            u32 lo = (u32)bmc[qt];
            u32 hi = (u32)(bmc[qt] >> 32);
            float p[4][4];
            float s = 0.f;
#pragma unroll
            for (int kt = 0; kt < 4; ++kt) {
                u32 word = (kt & 2) ? hi : lo;
                int  base = ((kt & 1) << 4) + (g << 2);
#pragma unroll
                for (int r = 0; r < 4; ++r) {
                    u32 bit = (word >> (base + r)) & 1u;
                    float val = bit ? st[kt][r] : 0.0f;   // masked -> exp2(0)=1
                    float e = exp2f(val);
                    p[kt][r] = e;
                    s += e;
                }
            }
            lsum[qt] += s;

            short8 pb0, pb1;
            pb0[0] = f2bf(p[0][0]); pb0[1] = f2bf(p[0][1]); pb0[2] = f2bf(p[0][2]); pb0[3] = f2bf(p[0][3]);
            pb0[4] = f2bf(p[1][0]); pb0[5] = f2bf(p[1][1]); pb0[6] = f2bf(p[1][2]); pb0[7] = f2bf(p[1][3]);
            pb1[0] = f2bf(p[2][0]); pb1[1] = f2bf(p[2][1]); pb1[2] = f2bf(p[2][2]); pb1[3] = f2bf(p[2][3]);
            pb1[4] = f2bf(p[3][0]); pb1[5] = f2bf(p[3][1]); pb1[6] = f2bf(p[3][2]); pb1[7] = f2bf(p[3][3]);

#pragma unroll
            for (int dt = 0; dt < 4; ++dt) {
                acc[qt][dt] = MFMA(vf[dt][0], pb0, acc[qt][dt]);
                acc[qt][dt] = MFMA(vf[dt][1], pb1, acc[qt][dt]);
            }
        }

        // 4) rotate mask bits
#pragma unroll
        for (int qt = 0; qt < 4; ++qt) bmc[qt] = bmn[qt];
    }

    // epilogue: reduce row sums across g-groups, normalize, store
#pragma unroll
    for (int qt = 0; qt < 4; ++qt) {
        float t0 = lsum[qt];
        t0 += __shfl_xor(t0, 16);
        t0 += __shfl_xor(t0, 32);
        float inv = 1.0f / t0;
        float* orow = obase + (long)(q0 + qt * 16 + c) * HD_;
#pragma unroll
        for (int dt = 0; dt < 4; ++dt) {
            f32x4 o = acc[qt][dt] * inv;
            __builtin_nontemporal_store(o, (f32x4*)(orow + dt * 16 + g * 4));
        }
    }
}

// ---- fallback (only if ws too small): round-1 style fused kernel ----
__global__ __launch_bounds__(256, 2)
void attn_fwd(const float* __restrict__ Q, const float* __restrict__ K,
              const float* __restrict__ V, const int* __restrict__ M,
              float* __restrict__ O)
{
    const float QSCALE = 0.125f * 1.44269504088896340736f;
    int orig = blockIdx.x;
    int wg   = (orig & 7) * 64 + (orig >> 3);
    int bh   = wg >> 3, qb = wg & 7;
    int b    = bh >> 4, h = bh & 15;
    int lane = threadIdx.x & 63, wave = threadIdx.x >> 6;
    int g = lane >> 4, c = lane & 15;
    int q0 = qb * 256 + wave * 64;

    const float* qbase = Q + (long)(b * S_) * HD_ + h * 64;
    const float* kbase = K + (long)(b * S_) * HD_ + h * 64;
    const float* vbase = V + (long)(b * S_) * HD_ + h * 64;
    const int*   mbase = M + ((long)bh << 22);
    float*       obase = O + (long)(b * S_) * HD_ + h * 64;

    short8 qf[4][2];
#pragma unroll
    for (int qt = 0; qt < 4; ++qt) {
        const float* qr = qbase + (long)(q0 + qt * 16 + c) * HD_;
#pragma unroll
        for (int hf = 0; hf < 2; ++hf) {
            f32x4 x0 = *(const f32x4*)(qr + hf * 32 + g * 8);
            f32x4 x1 = *(const f32x4*)(qr + hf * 32 + g * 8 + 4);
            short8 t;
            t[0] = f2bf(x0[0] * QSCALE); t[1] = f2bf(x0[1] * QSCALE);
            t[2] = f2bf(x0[2] * QSCALE); t[3] = f2bf(x0[3] * QSCALE);
            t[4] = f2bf(x1[0] * QSCALE); t[5] = f2bf(x1[1] * QSCALE);
            t[6] = f2bf(x1[2] * QSCALE); t[7] = f2bf(x1[3] * QSCALE);
            qf[qt][hf] = t;
        }
    }

    f32x4 acc[4][4];
#pragma unroll
    for (int qt = 0; qt < 4; ++qt)
#pragma unroll
        for (int dt = 0; dt < 4; ++dt) acc[qt][dt] = (f32x4){0.f, 0.f, 0.f, 0.f};
    float lsum[4] = {0.f, 0.f, 0.f, 0.f};

#pragma unroll 1
    for (int step = 0; step < STEPS_; ++step) {
        int kv0 = step * 64;
        short8 kf[4][2];
#pragma unroll
        for (int kt = 0; kt < 4; ++kt) {
            const float* kr = kbase + (long)(kv0 + kt * 16 + c) * HD_;
#pragma unroll
            for (int hf = 0; hf < 2; ++hf) {
                f32x4 x0 = *(const f32x4*)(kr + hf * 32 + g * 8);
                f32x4 x1 = *(const f32x4*)(kr + hf * 32 + g * 8 + 4);
                short8 t;
                t[0] = f2bf(x0[0]); t[1] = f2bf(x0[1]); t[2] = f2bf(x0[2]); t[3] = f2bf(x0[3]);
                t[4] = f2bf(x1[0]); t[5] = f2bf(x1[1]); t[6] = f2bf(x1[2]); t[7] = f2bf(x1[3]);
                kf[kt][hf] = t;
            }
        }
        short8 vf[4][2];
#pragma unroll
        for (int hf = 0; hf < 2; ++hf) {
            const float* vr[8];
#pragma unroll
            for (int i = 0; i < 4; ++i) {
                vr[i]     = vbase + (long)(kv0 + hf * 32 + g * 4 + i) * HD_ + c;
                vr[4 + i] = vbase + (long)(kv0 + hf * 32 + 16 + g * 4 + i) * HD_ + c;
            }
#pragma unroll
            for (int dt = 0; dt < 4; ++dt) {
                short8 t;
#pragma unroll
                for (int i = 0; i < 8; ++i) t[i] = f2bf(vr[i][dt * 16]);
                vf[dt][hf] = t;
            }
        }
#pragma unroll
        for (int qt = 0; qt < 4; ++qt) {
            f32x4 st[4];
#pragma unroll
            for (int kt = 0; kt < 4; ++kt) {
                f32x4 z = (f32x4){0.f, 0.f, 0.f, 0.f};
                z = MFMA(kf[kt][0], qf[qt][0], z);
                z = MFMA(kf[kt][1], qf[qt][1], z);
                st[kt] = z;
            }
            const int* mrp = mbase + ((long)(q0 + qt * 16 + c) << 11) + kv0 + g * 4;
            float p[4][4];
            float s = 0.f;
#pragma unroll
            for (int kt = 0; kt < 4; ++kt) {
                i32x4 mkv = *(const i32x4*)(mrp + kt * 16);
#pragma unroll
                for (int r = 0; r < 4; ++r) {
                    float val = (mkv[r] != 0) ? st[kt][r] : 0.0f;
                    float e = exp2f(val);
                    p[kt][r] = e;
                    s += e;
                }
            }
            lsum[qt] += s;
            short8 pb0, pb1;
            pb0[0] = f2bf(p[0][0]); pb0[1] = f2bf(p[0][1]); pb0[2] = f2bf(p[0][2]); pb0[3] = f2bf(p[0][3]);
            pb0[4] = f2bf(p[1][0]); pb0[5] = f2bf(p[1][1]); pb0[6] = f2bf(p[1][2]); pb0[7] = f2bf(p[1][3]);
            pb1[0] = f2bf(p[2][0]); pb1[1] = f2bf(p[2][1]); pb1[2] = f2bf(p[2][2]); pb1[3] = f2bf(p[2][3]);
            pb1[4] = f2bf(p[3][0]); pb1[5] = f2bf(p[3][1]); pb1[6] = f2bf(p[3][2]); pb1[7] = f2bf(p[3][3]);
#pragma unroll
            for (int dt = 0; dt < 4; ++dt) {
                acc[qt][dt] = MFMA(vf[dt][0], pb0, acc[qt][dt]);
                acc[qt][dt] = MFMA(vf[dt][1], pb1, acc[qt][dt]);
            }
        }
    }
#pragma unroll
    for (int qt = 0; qt < 4; ++qt) {
        float t0 = lsum[qt];
        t0 += __shfl_xor(t0, 16);
        t0 += __shfl_xor(t0, 32);
        float inv = 1.0f / t0;
        float* orow = obase + (long)(q0 + qt * 16 + c) * HD_;
#pragma unroll
        for (int dt = 0; dt < 4; ++dt) {
            f32x4 o = acc[qt][dt] * inv;
            *(f32x4*)(orow + dt * 16 + g * 4) = o;
        }
    }
}

extern "C" void kernel_launch(void* const* d_in, const int* in_sizes, int n_in,
                              void* d_out, int out_size, void* d_ws, size_t ws_size,
                              hipStream_t stream) {
    const float* q = (const float*)d_in[0];
    const float* k = (const float*)d_in[1];
    const float* v = (const float*)d_in[2];
    const int*   m = (const int*)d_in[3];
    float* out = (float*)d_out;

    size_t need = (size_t)2 * KP_ELEMS * sizeof(short) + (size_t)BM_WORDS * sizeof(u32); // 64 MiB
    if (ws_size >= need) {
        short* Kp = (short*)d_ws;
        short* Vp = Kp + KP_ELEMS;
        u32*   BM = (u32*)(Vp + KP_ELEMS);
        prepack_kv<<<dim3(4096), dim3(256), 0, stream>>>(k, v, Kp, Vp);
        compress_mask<<<dim3(32768), dim3(256), 0, stream>>>(m, BM);
        attn_fwd4<<<dim3(512), dim3(256), 0, stream>>>(q, Kp, Vp, BM, out);
    } else {
        attn_fwd<<<dim3(512), dim3(256), 0, stream>>>(q, k, v, m, out);
    }
}